// Round 2
// baseline (694.869 us; speedup 1.0000x reference)
//
#include <hip/hip_runtime.h>

#define N    1024
#define BSZ  32
#define PS   480     // per-sample param stride: 169 W13 + 147 w1 + 147 w2 + 9 kA
#define HID  100

// ---------------------------------------------------------------------------
// Kernel 1: per-sample MLPs + composed 13x13 kernel
// ---------------------------------------------------------------------------
__global__ __launch_bounds__(256) void prep_kernel(
    const float* __restrict__ kernelA,
    const float* __restrict__ fc1_w1, const float* __restrict__ fc1_b1,
    const float* __restrict__ fc1_w2, const float* __restrict__ fc1_b2,
    const float* __restrict__ fc2_w1, const float* __restrict__ fc2_b1,
    const float* __restrict__ fc2_w2, const float* __restrict__ fc2_b2,
    float* __restrict__ params)
{
    int b = blockIdx.x, t = threadIdx.x;
    __shared__ float w[9], h1[HID], h2[HID], w1[147], w2[147];
    if (t < 9) w[t] = kernelA[b * 9 + t];
    __syncthreads();
    if (t < HID) {
        float s1 = fc1_b1[t], s2 = fc2_b1[t];
        #pragma unroll
        for (int i = 0; i < 9; ++i) {
            s1 = fmaf(w[i], fc1_w1[i * HID + t], s1);
            s2 = fmaf(w[i], fc2_w1[i * HID + t], s2);
        }
        h1[t] = fmaxf(s1, 0.f);
        h2[t] = fmaxf(s2, 0.f);
    }
    __syncthreads();
    if (t < 147) {
        float s1 = fc1_b2[t], s2 = fc2_b2[t];
        for (int i = 0; i < HID; ++i) {
            s1 = fmaf(h1[i], fc1_w2[i * 147 + t], s1);
            s2 = fmaf(h2[i], fc2_w2[i * 147 + t], s2);
        }
        w1[t] = s1;
        w2[t] = s2;
    }
    __syncthreads();
    float* P = params + b * PS;
    if (t < 169) {   // W13[ey][ex] = sum_m sum_{d1+d2=e} w1[m,d1] * w2[m,d2]
        int ey = t / 13, ex = t % 13;
        float s = 0.f;
        for (int m = 0; m < 3; ++m)
            for (int d1y = 0; d1y < 7; ++d1y) {
                int d2y = ey - d1y;
                if (d2y < 0 || d2y > 6) continue;
                for (int d1x = 0; d1x < 7; ++d1x) {
                    int d2x = ex - d1x;
                    if (d2x < 0 || d2x > 6) continue;
                    s = fmaf(w1[m * 49 + d1y * 7 + d1x],
                             w2[m * 49 + d2y * 7 + d2x], s);
                }
            }
        P[t] = s;
    }
    if (t < 147) { P[169 + t] = w1[t]; P[316 + t] = w2[t]; }
    if (t < 9)   P[463 + t] = w[t];
}

// ---------------------------------------------------------------------------
// Kernel 2: interior — composed 13x13 conv over r (exact for px >=3 from edge)
// Tile 32x128, 256 threads, 4x4 outputs/thread.
// Micro-tile is 4 cols wide so adjacent lanes' ds_read_b128 are CONTIGUOUS
// (32 lanes cover 128 consecutive floats -> zero structural bank conflicts;
// the old 8-wide micro-tile left half the banks idle -> 2x LDS service time).
// ---------------------------------------------------------------------------
#define TR 32
#define TC 128
#define XR 46      // x tile rows  (TR + 14)
#define XC 142     // x tile cols  (TC + 14)
#define RRW 44     // r tile rows  (TR + 12)
#define RC 140     // r tile cols  (TC + 12)

__device__ __forceinline__ void load_win(const float* rp, float* win)
{
    #pragma unroll
    for (int q = 0; q < 4; ++q) {
        float4 v = *reinterpret_cast<const float4*>(rp + 4 * q);
        win[4 * q + 0] = v.x; win[4 * q + 1] = v.y;
        win[4 * q + 2] = v.z; win[4 * q + 3] = v.w;
    }
}

__device__ __forceinline__ void conv_row(const float* win, const float* __restrict__ P,
                                         int ky, float* accRow)
{
    #pragma unroll
    for (int c = 0; c < 13; ++c) {
        float tv = P[ky * 13 + c];          // block-uniform -> s_load
        #pragma unroll
        for (int j = 0; j < 4; ++j)
            accRow[j] = fmaf(win[c + j], tv, accRow[j]);
    }
}

__global__ __launch_bounds__(256, 3) void main_kernel(
    const float* __restrict__ X, const float* __restrict__ F,
    const float* __restrict__ params, float* __restrict__ out)
{
    __shared__ __align__(16) float xs[XR * XC];
    __shared__ __align__(16) float rs[RRW * RC];
    const int t  = threadIdx.x;
    const int b  = blockIdx.z;
    const int y0 = blockIdx.y * TR;
    const int x0 = blockIdx.x * TC;
    const float* P  = params + b * PS;
    const float* Xb = X + (size_t)b * N * N;
    const float* Fb = F + (size_t)b * N * N;
    float*       Ob = out + (size_t)b * N * N;

    // stage x tile (halo 7)
    for (int idx = t; idx < XR * XC; idx += 256) {
        int i = idx / XC, j = idx % XC;
        int gy = y0 - 7 + i, gx = x0 - 7 + j;
        xs[idx] = (gy >= 0 && gy < N && gx >= 0 && gx < N) ? Xb[gy * N + gx] : 0.f;
    }
    __syncthreads();

    float ka[9];
    #pragma unroll
    for (int i = 0; i < 9; ++i) ka[i] = P[463 + i];  // uniform -> SGPR

    // r = f - corr3x3(x, kA), zero outside image
    for (int idx = t; idx < RRW * RC; idx += 256) {
        int i = idx / RC, j = idx % RC;
        int gy = y0 - 6 + i, gx = x0 - 6 + j;
        float v = 0.f;
        if (gy >= 0 && gy < N && gx >= 0 && gx < N) {
            float s = 0.f;
            #pragma unroll
            for (int dy = 0; dy < 3; ++dy)
                #pragma unroll
                for (int dx = 0; dx < 3; ++dx)
                    s = fmaf(ka[dy * 3 + dx], xs[(i + dy) * XC + (j + dx)], s);
            v = Fb[gy * N + gx] - s;
        }
        rs[idx] = v;
    }
    __syncthreads();

    const int tx4 = (t & 31) * 4;   // col offset within tile (0..124)
    const int ty4 = (t >> 5) * 4;   // row offset within tile (0..28)
    const float* rbase = &rs[ty4 * RC + tx4];

    float acc[4][4] = {{0.f,0.f,0.f,0.f},{0.f,0.f,0.f,0.f},
                       {0.f,0.f,0.f,0.f},{0.f,0.f,0.f,0.f}};
    float win[16];

    // ramp-up: rr = 0..2
    load_win(rbase + 0 * RC, win);
    conv_row(win, P, 0, acc[0]);
    load_win(rbase + 1 * RC, win);
    conv_row(win, P, 1, acc[0]);
    conv_row(win, P, 0, acc[1]);
    load_win(rbase + 2 * RC, win);
    conv_row(win, P, 2, acc[0]);
    conv_row(win, P, 1, acc[1]);
    conv_row(win, P, 0, acc[2]);

    // steady: rr = 3..12, all 4 rows active, no branches
    for (int rr = 3; rr <= 12; ++rr) {
        load_win(rbase + rr * RC, win);
        #pragma unroll
        for (int i = 0; i < 4; ++i)
            conv_row(win, P, rr - i, acc[i]);
    }

    // ramp-down: rr = 13..15
    load_win(rbase + 13 * RC, win);
    conv_row(win, P, 12, acc[1]);
    conv_row(win, P, 11, acc[2]);
    conv_row(win, P, 10, acc[3]);
    load_win(rbase + 14 * RC, win);
    conv_row(win, P, 12, acc[2]);
    conv_row(win, P, 11, acc[3]);
    load_win(rbase + 15 * RC, win);
    conv_row(win, P, 12, acc[3]);

    // epilogue: out = x + G2 (full tiles, all in range)
    #pragma unroll
    for (int i = 0; i < 4; ++i) {
        const float* xp = &xs[(ty4 + i + 7) * XC + (tx4 + 7)];
        float4 o;
        o.x = xp[0] + acc[i][0]; o.y = xp[1] + acc[i][1];
        o.z = xp[2] + acc[i][2]; o.w = xp[3] + acc[i][3];
        *reinterpret_cast<float4*>(&Ob[(y0 + ty4 + i) * N + (x0 + tx4)]) = o;
    }
}

// ---------------------------------------------------------------------------
// Kernel 3: exact two-stage recompute of the width-3 border band (overwrites).
// Templated on EDGE so all index selects constant-fold and loops unroll.
// EDGE: 0 top, 1 bottom, 2 left, 3 right.
// ---------------------------------------------------------------------------
#define AXX 14     // x across size
#define AXU 142    // x along size
#define ARR 12     // r across size
#define ARU 140    // r along size
#define ATA 6      // tmp across size
#define ATU 134    // tmp along size

template<int EDGE>
__global__ __launch_bounds__(256) void border_kernel(
    const float* __restrict__ X, const float* __restrict__ F,
    const float* __restrict__ params, float* __restrict__ out)
{
    __shared__ float xs[AXX * AXU];
    __shared__ float rs[ARR * ARU];
    __shared__ float tmp[3 * ATA * ATU];
    __shared__ float sw1[147], sw2[147];

    const int  t = threadIdx.x;
    const int  b = blockIdx.y;
    const int  s = blockIdx.x;
    constexpr bool vert = (EDGE >= 2);
    constexpr bool hi   = (EDGE == 1) || (EDGE == 3);
    constexpr int  T0   = hi ? (N - 6) : 0;  // tmp across origin
    constexpr int  V0   = hi ? (N - 3) : 0;  // output across origin
    constexpr int  D    = hi ? 3 : 0;        // V0 - T0
    const int  u0   = vert ? (3 + s * 128) : (s * 128);
    const int  acr0x = T0 - 4, al0x = u0 - 7;
    const int  acr0r = T0 - 3, al0r = u0 - 6;

    const float* P  = params + b * PS;
    const float* Xb = X + (size_t)b * N * N;
    const float* Fb = F + (size_t)b * N * N;
    float*       Ob = out + (size_t)b * N * N;

    if (t < 147) { sw1[t] = P[169 + t]; sw2[t] = P[316 + t]; }
    float ka[9];
    #pragma unroll
    for (int i = 0; i < 9; ++i) ka[i] = P[463 + i];

    // stage x (zero-extended)
    for (int idx = t; idx < AXX * AXU; idx += 256) {
        int a = vert ? (idx % AXX) : (idx / AXU);
        int u = vert ? (idx / AXX) : (idx % AXU);
        int ga = acr0x + a, gl = al0x + u;
        int gy = vert ? gl : ga, gx = vert ? ga : gl;
        xs[a * AXU + u] =
            (gy >= 0 && gy < N && gx >= 0 && gx < N) ? Xb[gy * N + gx] : 0.f;
    }
    __syncthreads();

    // r = f - corr3x3(x,kA), zero outside image
    for (int idx = t; idx < ARR * ARU; idx += 256) {
        int a = vert ? (idx % ARR) : (idx / ARU);
        int u = vert ? (idx / ARR) : (idx % ARU);
        int ga = acr0r + a, gl = al0r + u;
        int gy = vert ? gl : ga, gx = vert ? ga : gl;
        float v = 0.f;
        if (gy >= 0 && gy < N && gx >= 0 && gx < N) {
            float sc = 0.f;
            #pragma unroll
            for (int da = 0; da < 3; ++da)
                #pragma unroll
                for (int dl = 0; dl < 3; ++dl)
                    sc = fmaf(ka[vert ? (dl * 3 + da) : (da * 3 + dl)],
                              xs[(a + da) * AXU + (u + dl)], sc);
            v = Fb[gy * N + gx] - sc;
        }
        rs[a * ARU + u] = v;
    }
    __syncthreads();

    // tmp[m, a, u]: zero if along position outside image (reference zeroing)
    for (int idx = t; idx < 3 * ATA * ATU; idx += 256) {
        int m   = idx / (ATA * ATU);
        int rem = idx - m * (ATA * ATU);
        int a = rem / ATU, u = rem % ATU;
        int gl = (u0 - 3) + u;
        float sc = 0.f;
        if (gl >= 0 && gl < N) {
            #pragma unroll
            for (int da = 0; da < 7; ++da)
                #pragma unroll
                for (int dl = 0; dl < 7; ++dl)
                    sc = fmaf(sw1[m * 49 + (vert ? (dl * 7 + da) : (da * 7 + dl))],
                              rs[(a + da) * ARU + (u + dl)], sc);
        }
        tmp[idx] = sc;
    }
    __syncthreads();

    // outputs: 3 across x 128 along
    for (int idx = t; idx < 3 * 128; idx += 256) {
        int v = idx / 128, u = idx % 128;
        int gl = u0 + u, ga = V0 + v;
        if (vert && gl >= N - 3) continue;   // partial last vertical segment
        float sc = 0.f;
        #pragma unroll
        for (int m = 0; m < 3; ++m)
            #pragma unroll
            for (int d2a = 0; d2a < 7; ++d2a) {
                int aT = v + d2a - 3 + D;    // tmp across index; OOR => ref zeroes
                if (aT < 0 || aT >= ATA) continue;
                #pragma unroll
                for (int d2l = 0; d2l < 7; ++d2l)
                    sc = fmaf(sw2[m * 49 + (vert ? (d2l * 7 + d2a) : (d2a * 7 + d2l))],
                              tmp[(m * ATA + aT) * ATU + (u + d2l)], sc);
            }
        int gy = vert ? gl : ga, gx = vert ? ga : gl;
        float xv = xs[(ga - acr0x) * AXU + (gl - al0x)];
        Ob[gy * N + gx] = xv + sc;
    }
}

// ---------------------------------------------------------------------------
extern "C" void kernel_launch(void* const* d_in, const int* in_sizes, int n_in,
                              void* d_out, int out_size, void* d_ws, size_t ws_size,
                              hipStream_t stream)
{
    const float* x    = (const float*)d_in[0];
    const float* f    = (const float*)d_in[1];
    const float* kA   = (const float*)d_in[2];
    const float* f1w1 = (const float*)d_in[3];
    const float* f1b1 = (const float*)d_in[4];
    const float* f1w2 = (const float*)d_in[5];
    const float* f1b2 = (const float*)d_in[6];
    const float* f2w1 = (const float*)d_in[7];
    const float* f2b1 = (const float*)d_in[8];
    const float* f2w2 = (const float*)d_in[9];
    const float* f2b2 = (const float*)d_in[10];
    float* out    = (float*)d_out;
    float* params = (float*)d_ws;   // BSZ * PS floats = 61440 B

    prep_kernel<<<BSZ, 256, 0, stream>>>(kA, f1w1, f1b1, f1w2, f1b2,
                                         f2w1, f2b1, f2w2, f2b2, params);
    main_kernel<<<dim3(N / TC, N / TR, BSZ), 256, 0, stream>>>(x, f, params, out);
    border_kernel<0><<<dim3(8, BSZ), 256, 0, stream>>>(x, f, params, out);
    border_kernel<1><<<dim3(8, BSZ), 256, 0, stream>>>(x, f, params, out);
    border_kernel<2><<<dim3(8, BSZ), 256, 0, stream>>>(x, f, params, out);
    border_kernel<3><<<dim3(8, BSZ), 256, 0, stream>>>(x, f, params, out);
}

// Round 3
// 542.700 us; speedup vs baseline: 1.2804x; 1.2804x over previous
//
#include <hip/hip_runtime.h>

#define N    1024
#define BSZ  32
#define PS   480     // per-sample param stride: 169 W13 + 147 w1 + 147 w2 + 9 kA
#define HID  100

// ---------------------------------------------------------------------------
// Kernel 1: per-sample MLPs + composed 13x13 kernel
// ---------------------------------------------------------------------------
__global__ __launch_bounds__(256) void prep_kernel(
    const float* __restrict__ kernelA,
    const float* __restrict__ fc1_w1, const float* __restrict__ fc1_b1,
    const float* __restrict__ fc1_w2, const float* __restrict__ fc1_b2,
    const float* __restrict__ fc2_w1, const float* __restrict__ fc2_b1,
    const float* __restrict__ fc2_w2, const float* __restrict__ fc2_b2,
    float* __restrict__ params)
{
    int b = blockIdx.x, t = threadIdx.x;
    __shared__ float w[9], h1[HID], h2[HID], w1[147], w2[147];
    if (t < 9) w[t] = kernelA[b * 9 + t];
    __syncthreads();
    if (t < HID) {
        float s1 = fc1_b1[t], s2 = fc2_b1[t];
        #pragma unroll
        for (int i = 0; i < 9; ++i) {
            s1 = fmaf(w[i], fc1_w1[i * HID + t], s1);
            s2 = fmaf(w[i], fc2_w1[i * HID + t], s2);
        }
        h1[t] = fmaxf(s1, 0.f);
        h2[t] = fmaxf(s2, 0.f);
    }
    __syncthreads();
    if (t < 147) {
        float s1 = fc1_b2[t], s2 = fc2_b2[t];
        for (int i = 0; i < HID; ++i) {
            s1 = fmaf(h1[i], fc1_w2[i * 147 + t], s1);
            s2 = fmaf(h2[i], fc2_w2[i * 147 + t], s2);
        }
        w1[t] = s1;
        w2[t] = s2;
    }
    __syncthreads();
    float* P = params + b * PS;
    if (t < 169) {   // W13[ey][ex] = sum_m sum_{d1+d2=e} w1[m,d1] * w2[m,d2]
        int ey = t / 13, ex = t % 13;
        float s = 0.f;
        for (int m = 0; m < 3; ++m)
            for (int d1y = 0; d1y < 7; ++d1y) {
                int d2y = ey - d1y;
                if (d2y < 0 || d2y > 6) continue;
                for (int d1x = 0; d1x < 7; ++d1x) {
                    int d2x = ex - d1x;
                    if (d2x < 0 || d2x > 6) continue;
                    s = fmaf(w1[m * 49 + d1y * 7 + d1x],
                             w2[m * 49 + d2y * 7 + d2x], s);
                }
            }
        P[t] = s;
    }
    if (t < 147) { P[169 + t] = w1[t]; P[316 + t] = w2[t]; }
    if (t < 9)   P[463 + t] = w[t];
}

// ---------------------------------------------------------------------------
// Kernel 2: interior — composed 13x13 conv over r.
// SINGLE in-place LDS buffer (26.5 KB -> 6 blocks/CU): stage x, compute r
// into registers with b128 stencil reads, write r back into same buffer.
// 4x4 outputs/thread, 4-wide micro-tile (contiguous wave b128 -> no conflicts).
// Epilogue re-reads x from global (coalesced b128) instead of LDS.
// ---------------------------------------------------------------------------
#define TR 32
#define TC 128
#define XR 46      // x rows (TR+14)
#define XC 144     // x row pitch (TC+14 rounded to mult of 4 for b128 align)
#define RRW 44     // r rows (TR+12)
#define RC 140     // r row pitch (TC+12, 560B = 16B-aligned rows)
#define NQ 1540    // r quads: 44 * 35

__device__ __forceinline__ void conv_row(const float* win, const float* __restrict__ P,
                                         int ky, float* accRow)
{
    #pragma unroll
    for (int c = 0; c < 13; ++c) {
        float tv = P[ky * 13 + c];          // block-uniform -> scalar load
        #pragma unroll
        for (int j = 0; j < 4; ++j)
            accRow[j] = fmaf(win[c + j], tv, accRow[j]);
    }
}

__global__ __launch_bounds__(256, 6) void main_kernel(
    const float* __restrict__ X, const float* __restrict__ F,
    const float* __restrict__ params, float* __restrict__ out)
{
    __shared__ __align__(16) float buf[XR * XC];   // 26496 B
    const int t  = threadIdx.x;
    const int b  = blockIdx.z;
    const int y0 = blockIdx.y * TR;
    const int x0 = blockIdx.x * TC;
    const float* P  = params + b * PS;
    const float* Xb = X + (size_t)b * N * N;
    const float* Fb = F + (size_t)b * N * N;
    float*       Ob = out + (size_t)b * N * N;

    // ---- phase 1: stage x tile (halo 7), zero-extended
    for (int idx = t; idx < XR * XC; idx += 256) {
        int i = idx / XC, j = idx - i * XC;
        int gy = y0 - 7 + i, gx = x0 - 7 + j;
        buf[idx] = (gy >= 0 && gy < N && gx >= 0 && gx < N) ? Xb[gy * N + gx] : 0.f;
    }
    __syncthreads();

    float ka[9];
    #pragma unroll
    for (int i = 0; i < 9; ++i) ka[i] = P[463 + i];  // uniform -> SGPR

    // ---- phase 2: r = f - corr3x3(x,kA) into registers, quad-granular.
    // quad idx: row i = idx/35, col j = (idx%35)*4. Reads 3 rows x 8 floats.
    float rq[7][4];
    #pragma unroll
    for (int k = 0; k < 7; ++k) {
        int idx = t + k * 256;
        if (idx < NQ) {
            int i = idx / 35;
            int j = (idx - i * 35) * 4;
            const float* xr = &buf[i * XC + j];
            float s[4] = {0.f, 0.f, 0.f, 0.f};
            #pragma unroll
            for (int dy = 0; dy < 3; ++dy) {
                float w8[8];
                float4 v0 = *reinterpret_cast<const float4*>(xr + dy * XC);
                float4 v1 = *reinterpret_cast<const float4*>(xr + dy * XC + 4);
                w8[0] = v0.x; w8[1] = v0.y; w8[2] = v0.z; w8[3] = v0.w;
                w8[4] = v1.x; w8[5] = v1.y; w8[6] = v1.z; w8[7] = v1.w;
                #pragma unroll
                for (int dx = 0; dx < 3; ++dx)
                    #pragma unroll
                    for (int c = 0; c < 4; ++c)
                        s[c] = fmaf(ka[dy * 3 + dx], w8[dx + c], s[c]);
            }
            int gy = y0 - 6 + i, gxb = x0 - 6 + j;
            #pragma unroll
            for (int c = 0; c < 4; ++c) {
                int gx = gxb + c;
                float v = 0.f;
                if (gy >= 0 && gy < N && gx >= 0 && gx < N)
                    v = Fb[gy * N + gx] - s[c];
                rq[k][c] = v;
            }
        }
    }
    __syncthreads();

    // ---- phase 3: write r back into buf (RC pitch), b128, contiguous lanes
    #pragma unroll
    for (int k = 0; k < 7; ++k) {
        int idx = t + k * 256;
        if (idx < NQ) {
            int i = idx / 35;
            int j = (idx - i * 35) * 4;
            float4 v; v.x = rq[k][0]; v.y = rq[k][1]; v.z = rq[k][2]; v.w = rq[k][3];
            *reinterpret_cast<float4*>(&buf[i * RC + j]) = v;
        }
    }
    __syncthreads();

    // ---- phase 4: 13x13 composed conv, 4x4 per thread
    const int tx4 = (t & 31) * 4;   // col offset (0..124)
    const int ty4 = (t >> 5) * 4;   // row offset (0..28)
    const float* rbase = &buf[ty4 * RC + tx4];

    float acc[4][4] = {{0.f,0.f,0.f,0.f},{0.f,0.f,0.f,0.f},
                       {0.f,0.f,0.f,0.f},{0.f,0.f,0.f,0.f}};
    float win[16];

    #define LOAD_WIN(rr)                                                     \
        { float4 v0 = *reinterpret_cast<const float4*>(rbase + (rr) * RC);   \
          float4 v1 = *reinterpret_cast<const float4*>(rbase + (rr) * RC + 4);\
          float4 v2 = *reinterpret_cast<const float4*>(rbase + (rr) * RC + 8);\
          float4 v3 = *reinterpret_cast<const float4*>(rbase + (rr) * RC + 12);\
          win[0]=v0.x; win[1]=v0.y; win[2]=v0.z; win[3]=v0.w;                \
          win[4]=v1.x; win[5]=v1.y; win[6]=v1.z; win[7]=v1.w;                \
          win[8]=v2.x; win[9]=v2.y; win[10]=v2.z; win[11]=v2.w;              \
          win[12]=v3.x; win[13]=v3.y; win[14]=v3.z; win[15]=v3.w; }

    LOAD_WIN(0);
    conv_row(win, P, 0, acc[0]);
    LOAD_WIN(1);
    conv_row(win, P, 1, acc[0]);
    conv_row(win, P, 0, acc[1]);
    LOAD_WIN(2);
    conv_row(win, P, 2, acc[0]);
    conv_row(win, P, 1, acc[1]);
    conv_row(win, P, 0, acc[2]);

    for (int rr = 3; rr <= 12; ++rr) {
        LOAD_WIN(rr);
        #pragma unroll
        for (int i = 0; i < 4; ++i)
            conv_row(win, P, rr - i, acc[i]);
    }

    LOAD_WIN(13);
    conv_row(win, P, 12, acc[1]);
    conv_row(win, P, 11, acc[2]);
    conv_row(win, P, 10, acc[3]);
    LOAD_WIN(14);
    conv_row(win, P, 12, acc[2]);
    conv_row(win, P, 11, acc[3]);
    LOAD_WIN(15);
    conv_row(win, P, 12, acc[3]);

    // ---- epilogue: out = x + G2 (x re-read from global, coalesced b128)
    #pragma unroll
    for (int i = 0; i < 4; ++i) {
        const float4 xq = *reinterpret_cast<const float4*>(
            &Xb[(y0 + ty4 + i) * N + (x0 + tx4)]);
        float4 o;
        o.x = xq.x + acc[i][0]; o.y = xq.y + acc[i][1];
        o.z = xq.z + acc[i][2]; o.w = xq.w + acc[i][3];
        *reinterpret_cast<float4*>(&Ob[(y0 + ty4 + i) * N + (x0 + tx4)]) = o;
    }
}

// ---------------------------------------------------------------------------
// Kernel 3: exact two-stage recompute of the width-3 border band (overwrites).
// ONE launch, 64-px segments, all 4 edges: grid (64, B). edge = bx>>4.
// "across" = perpendicular-to-edge coord, "along" = edge direction.
// ---------------------------------------------------------------------------
#define SEG 64
#define AXX 14          // x across size
#define AXU (SEG + 14)  // x along size   78
#define ARR 12          // r across size
#define ARU (SEG + 12)  // r along size   76
#define ATA 6           // tmp across size
#define ATU (SEG + 6)   // tmp along size 70

__global__ __launch_bounds__(256) void border_kernel(
    const float* __restrict__ X, const float* __restrict__ F,
    const float* __restrict__ params, float* __restrict__ out)
{
    __shared__ float xs[AXX * AXU];
    __shared__ float rs[ARR * ARU];
    __shared__ float tmp[3 * ATA * ATU];
    __shared__ float sw1[147], sw2[147];

    const int  t    = threadIdx.x;
    const int  b    = blockIdx.y;
    const int  seg  = blockIdx.x;
    const int  edge = seg >> 4;          // 0 top, 1 bottom, 2 left, 3 right
    const int  s    = seg & 15;
    const bool vert = edge >= 2;
    const bool hi   = (edge == 1) || (edge == 3);
    const int  T0   = hi ? (N - 6) : 0;  // tmp across origin
    const int  V0   = hi ? (N - 3) : 0;  // output across origin
    const int  D    = hi ? 3 : 0;        // V0 - T0
    const int  u0   = vert ? (3 + s * SEG) : (s * SEG);
    const int  acr0x = T0 - 4, al0x = u0 - 7;
    const int  acr0r = T0 - 3, al0r = u0 - 6;

    const float* P  = params + b * PS;
    const float* Xb = X + (size_t)b * N * N;
    const float* Fb = F + (size_t)b * N * N;
    float*       Ob = out + (size_t)b * N * N;

    if (t < 147) { sw1[t] = P[169 + t]; sw2[t] = P[316 + t]; }
    float ka[9];
    #pragma unroll
    for (int i = 0; i < 9; ++i) ka[i] = P[463 + i];

    // stage x (zero-extended)
    for (int idx = t; idx < AXX * AXU; idx += 256) {
        int a = vert ? (idx % AXX) : (idx / AXU);
        int u = vert ? (idx / AXX) : (idx % AXU);
        int ga = acr0x + a, gl = al0x + u;
        int gy = vert ? gl : ga, gx = vert ? ga : gl;
        xs[a * AXU + u] =
            (gy >= 0 && gy < N && gx >= 0 && gx < N) ? Xb[gy * N + gx] : 0.f;
    }
    __syncthreads();

    // r = f - corr3x3(x,kA), zero outside image
    for (int idx = t; idx < ARR * ARU; idx += 256) {
        int a = vert ? (idx % ARR) : (idx / ARU);
        int u = vert ? (idx / ARR) : (idx % ARU);
        int ga = acr0r + a, gl = al0r + u;
        int gy = vert ? gl : ga, gx = vert ? ga : gl;
        float v = 0.f;
        if (gy >= 0 && gy < N && gx >= 0 && gx < N) {
            float sc = 0.f;
            #pragma unroll
            for (int da = 0; da < 3; ++da)
                #pragma unroll
                for (int dl = 0; dl < 3; ++dl)
                    sc = fmaf(ka[vert ? (dl * 3 + da) : (da * 3 + dl)],
                              xs[(a + da) * AXU + (u + dl)], sc);
            v = Fb[gy * N + gx] - sc;
        }
        rs[a * ARU + u] = v;
    }
    __syncthreads();

    // tmp[m, a, u]: zero if along position outside image (reference zeroing)
    for (int idx = t; idx < 3 * ATA * ATU; idx += 256) {
        int m   = idx / (ATA * ATU);
        int rem = idx - m * (ATA * ATU);
        int a = rem / ATU, u = rem % ATU;
        int gl = (u0 - 3) + u;
        float sc = 0.f;
        if (gl >= 0 && gl < N) {
            #pragma unroll
            for (int da = 0; da < 7; ++da)
                #pragma unroll
                for (int dl = 0; dl < 7; ++dl)
                    sc = fmaf(sw1[m * 49 + (vert ? (dl * 7 + da) : (da * 7 + dl))],
                              rs[(a + da) * ARU + (u + dl)], sc);
        }
        tmp[idx] = sc;
    }
    __syncthreads();

    // outputs: 3 across x SEG along
    for (int idx = t; idx < 3 * SEG; idx += 256) {
        int v = idx / SEG, u = idx - (idx / SEG) * SEG;
        int gl = u0 + u, ga = V0 + v;
        if (vert && gl >= N - 3) continue;   // partial last vertical segment
        float sc = 0.f;
        #pragma unroll
        for (int m = 0; m < 3; ++m)
            #pragma unroll
            for (int d2a = 0; d2a < 7; ++d2a) {
                int aT = v + d2a - 3 + D;    // tmp across index; OOR => ref zeroes
                if (aT < 0 || aT >= ATA) continue;
                #pragma unroll
                for (int d2l = 0; d2l < 7; ++d2l)
                    sc = fmaf(sw2[m * 49 + (vert ? (d2l * 7 + d2a) : (d2a * 7 + d2l))],
                              tmp[(m * ATA + aT) * ATU + (u + d2l)], sc);
            }
        int gy = vert ? gl : ga, gx = vert ? ga : gl;
        float xv = xs[(ga - acr0x) * AXU + (gl - al0x)];
        Ob[gy * N + gx] = xv + sc;
    }
}

// ---------------------------------------------------------------------------
extern "C" void kernel_launch(void* const* d_in, const int* in_sizes, int n_in,
                              void* d_out, int out_size, void* d_ws, size_t ws_size,
                              hipStream_t stream)
{
    const float* x    = (const float*)d_in[0];
    const float* f    = (const float*)d_in[1];
    const float* kA   = (const float*)d_in[2];
    const float* f1w1 = (const float*)d_in[3];
    const float* f1b1 = (const float*)d_in[4];
    const float* f1w2 = (const float*)d_in[5];
    const float* f1b2 = (const float*)d_in[6];
    const float* f2w1 = (const float*)d_in[7];
    const float* f2b1 = (const float*)d_in[8];
    const float* f2w2 = (const float*)d_in[9];
    const float* f2b2 = (const float*)d_in[10];
    float* out    = (float*)d_out;
    float* params = (float*)d_ws;   // BSZ * PS floats = 61440 B

    prep_kernel<<<BSZ, 256, 0, stream>>>(kA, f1w1, f1b1, f1w2, f1b2,
                                         f2w1, f2b1, f2w2, f2b2, params);
    main_kernel<<<dim3(N / TC, N / TR, BSZ), 256, 0, stream>>>(x, f, params, out);
    border_kernel<<<dim3(64, BSZ), 256, 0, stream>>>(x, f, params, out);
}